// Round 6
// baseline (107.369 us; speedup 1.0000x reference)
//
#include <hip/hip_runtime.h>

typedef __bf16 bf16;
typedef __bf16 bf16x4 __attribute__((ext_vector_type(4)));
typedef __bf16 bf16x8 __attribute__((ext_vector_type(8)));
typedef float f32x4 __attribute__((ext_vector_type(4)));
typedef float f32x16 __attribute__((ext_vector_type(16)));
typedef unsigned u32x4 __attribute__((ext_vector_type(4)));

#define DEV __device__ __forceinline__

typedef const __attribute__((address_space(1))) void gvoid_t;
typedef __attribute__((address_space(3))) void lvoid_t;

DEV void gload_lds16(const void* g, void* l) {
  __builtin_amdgcn_global_load_lds((gvoid_t*)g, (lvoid_t*)l, 16, 0, 0);
}

DEV f32x4 mfma16(bf16x8 a, bf16x8 b, f32x4 c) {
  return __builtin_amdgcn_mfma_f32_16x16x32_bf16(a, b, c, 0, 0, 0);
}
DEV f32x16 mfma32(bf16x8 a, bf16x8 b, f32x16 c) {
  return __builtin_amdgcn_mfma_f32_32x32x16_bf16(a, b, c, 0, 0, 0);
}

DEV unsigned pk2(float lo, float hi) {
  unsigned r;
  asm("v_cvt_pk_bf16_f32 %0, %1, %2" : "=v"(r) : "v"(lo), "v"(hi));
  return r;
}

// scores in exp2 domain: Q pre-scaled by 0.125 * log2(e) in the GEMM epilogue.
#define QSCALE 0.18033688011112042f

// ---------------------------------------------------------------------------
// Kernel A: fused f32 -> bf16 conversion of hidden_states + Wq|Wk|Wv.
// ---------------------------------------------------------------------------
__global__ __launch_bounds__(256) void cvt_all(
    const float* __restrict__ hs, const float* __restrict__ Wq,
    const float* __restrict__ Wk, const float* __restrict__ Wv,
    bf16* __restrict__ Xb, bf16* __restrict__ Wb) {
  const int i = blockIdx.x * 256 + threadIdx.x;  // float4 index
  const float* src;
  bf16* dst;
  int off;
  if (i < 1048576) {
    src = hs; dst = Xb; off = i;
  } else {
    const int j = i - 1048576;
    const int sel = j >> 18;
    off = j & 262143;
    src = (sel == 0) ? Wq : (sel == 1) ? Wk : Wv;
    dst = Wb + (size_t)sel * 1048576;
  }
  float4 f = reinterpret_cast<const float4*>(src)[off];
  bf16x4 o;
  o[0] = (bf16)f.x; o[1] = (bf16)f.y; o[2] = (bf16)f.z; o[3] = (bf16)f.w;
  reinterpret_cast<bf16x4*>(dst)[off] = o;
}

// ---------------------------------------------------------------------------
// Kernel B: fused QKV projection GEMM (unchanged from R5).
// ---------------------------------------------------------------------------
__global__ __launch_bounds__(256) void gemm_qkv(
    const bf16* __restrict__ X, const bf16* __restrict__ W,
    const float* __restrict__ bq, const float* __restrict__ bk,
    const float* __restrict__ bv,
    bf16* __restrict__ Q, bf16* __restrict__ Kb, bf16* __restrict__ Vt) {
  __shared__ bf16 As[128 * 64];
  __shared__ bf16 Bs[128 * 64];
  const int t = threadIdx.x;
  const int lane = t & 63, w = t >> 6;
  const int wr = w >> 1, wc = w & 1;
  const int bid = blockIdx.x;
  const int swzb = (bid & 7) * 96 + (bid >> 3);  // XCD swizzle, 768%8==0
  const int m0 = (swzb / 24) * 128;
  const int n0 = (swzb % 24) * 128;
  const int cl = lane & 15, g8 = (lane >> 4) * 8;

  f32x4 acc[4][4];
  for (int mi = 0; mi < 4; ++mi)
    for (int ni = 0; ni < 4; ++ni)
      for (int r = 0; r < 4; ++r) acc[mi][ni][r] = 0.0f;

  for (int k0 = 0; k0 < 1024; k0 += 64) {
#pragma unroll
    for (int i = 0; i < 4; ++i) {
      int c = i * 256 + t;
      int row = c >> 3, col8 = (c & 7) * 8;
      gload_lds16(X + (size_t)(m0 + row) * 1024 + k0 + col8, As + c * 8);
      gload_lds16(W + (size_t)(n0 + row) * 1024 + k0 + col8, Bs + c * 8);
    }
    __syncthreads();
#pragma unroll
    for (int kk = 0; kk < 64; kk += 32) {
      bf16x8 a[4], b[4];
#pragma unroll
      for (int mi = 0; mi < 4; ++mi)
        a[mi] = *(const bf16x8*)&As[(wr * 64 + mi * 16 + cl) * 64 + kk + g8];
#pragma unroll
      for (int ni = 0; ni < 4; ++ni)
        b[ni] = *(const bf16x8*)&Bs[(wc * 64 + ni * 16 + cl) * 64 + kk + g8];
      __builtin_amdgcn_s_setprio(1);
#pragma unroll
      for (int mi = 0; mi < 4; ++mi)
#pragma unroll
        for (int ni = 0; ni < 4; ++ni)
          acc[mi][ni] = mfma16(a[mi], b[ni], acc[mi][ni]);
      __builtin_amdgcn_s_setprio(0);
    }
    __syncthreads();
  }

  const int rq = (lane >> 4) * 4;
#pragma unroll
  for (int mi = 0; mi < 4; ++mi) {
#pragma unroll
    for (int ni = 0; ni < 4; ++ni) {
      const int n = n0 + wc * 64 + ni * 16 + cl;
      const int mbase = m0 + wr * 64 + mi * 16 + rq;
      const int b = mbase >> 11, s0 = mbase & 2047;
      if (n < 1024) {
        const float bias = bq[n];
        const int h = n >> 6, hd = n & 63;
#pragma unroll
        for (int r = 0; r < 4; ++r)
          Q[(((size_t)(b * 16 + h)) * 2048 + s0 + r) * 64 + hd] =
              (bf16)((acc[mi][ni][r] + bias) * QSCALE);
      } else if (n < 2048) {
        const int n2 = n - 1024;
        const float bias = bk[n2];
        const int h = n2 >> 6, hd = n2 & 63;
#pragma unroll
        for (int r = 0; r < 4; ++r)
          Kb[(((size_t)(b * 16 + h)) * 2048 + s0 + r) * 64 + hd] =
              (bf16)(acc[mi][ni][r] + bias);
      } else {
        const int n2 = n - 2048;
        const float bias = bv[n2];
        const int h = n2 >> 6, hd = n2 & 63;
        bf16x4 pk;
#pragma unroll
        for (int r = 0; r < 4; ++r) pk[r] = (bf16)(acc[mi][ni][r] + bias);
        *(bf16x4*)&Vt[(((size_t)(b * 16 + h)) * 64 + hd) * 2048 + s0] = pk;
      }
    }
  }
}

// ---------------------------------------------------------------------------
// Kernel C: causal flash attention v6 — 32x32 swapped-QK^T, in-register P.
// Block = 4 waves (256 thr); waves 0-1 own q-tile 31-p (32 rows each),
// waves 2-3 own q-tile p. KVBLK=64, double-buffered LDS packed [32][128]
// with 4-bit XOR swizzle (2-way = free). QK^T computed as mfma32(K, Q^T)
// so each lane holds P-row (q = lane&31) in registers: fixed-max softmax
// (acc init -12, p = exp2(s)), rowsum = thread-local adds + shfl_xor(32),
// P->A-frags via v_cvt_pk_bf16_f32 + shfl_xor(32) + cndmask. No P LDS.
// ---------------------------------------------------------------------------
__global__ __launch_bounds__(256, 2) void flash_attn(
    const bf16* __restrict__ Q, const bf16* __restrict__ K,
    const bf16* __restrict__ Vt, const int* __restrict__ amask,
    float* __restrict__ out) {
  __shared__ bf16 Ks[2][32 * 128];
  __shared__ bf16 Vs[2][32 * 128];
  __shared__ unsigned long long mk[32];
  const int t = threadIdx.x, lane = t & 63, w = t >> 6;
  const int bh = blockIdx.x & 31;  // same bh -> same XCD
  const int p = blockIdx.x >> 5;   // 0..15
  const int b = bh >> 4, h = bh & 15;
  const int qt = (w < 2) ? (31 - p) : p;
  const int row0 = qt * 64 + (w & 1) * 32;
  const int ntiles = 32 - p;
  const int r31 = lane & 31, hi = lane >> 5;
  const int swz = (r31 & 15) << 4;

  const bf16* Qp = Q + (size_t)bh * 2048 * 64;
  const bf16* Kp = K + (size_t)bh * 2048 * 64;
  const bf16* Vp = Vt + (size_t)bh * 64 * 2048;

  // Q^T B-fragments: lane holds col q=r31, k(hd) = hdk*16 + hi*8 .. +8
  bf16x8 qf[4];
#pragma unroll
  for (int hdk = 0; hdk < 4; ++hdk)
    qf[hdk] = *(const bf16x8*)&Qp[(size_t)(row0 + r31) * 64 + hdk * 16 + hi * 8];

  f32x16 o[2];
#pragma unroll
  for (int hb = 0; hb < 2; ++hb)
#pragma unroll
    for (int rg = 0; rg < 16; ++rg) o[hb][rg] = 0.0f;
  float ls = 0.0f;

  // prologue: pad-mask ballots for all 32 tiles, stage tile 0 into buf 0.
#pragma unroll
  for (int i = 0; i < 8; ++i) {
    const int kt = w * 8 + i;
    const unsigned long long bal =
        __ballot(amask[b * 2048 + kt * 64 + lane] != 0);
    if (lane == 0) mk[kt] = bal;
  }
  // staging: LDS [32][128] packed; row r holds rows {r, r+32} of the 64-wide
  // global tile; slot s holds global 8-elem block u = s ^ (r&15).
#define STAGE(BUFN, KVB)                                                    \
  do {                                                                      \
    _Pragma("unroll") for (int i_ = 0; i_ < 2; ++i_) {                      \
      const int c_ = i_ * 256 + t;                                          \
      const int r_ = c_ >> 4, u_ = (c_ & 15) ^ (r_ & 15);                   \
      const int rr_ = (u_ >> 3) * 32 + r_, gb_ = (u_ & 7) * 8;              \
      gload_lds16(Kp + (size_t)((KVB) + rr_) * 64 + gb_,                    \
                  (bf16*)Ks + (BUFN)*4096 + c_ * 8);                        \
      gload_lds16(Vp + (size_t)rr_ * 2048 + (KVB) + gb_,                    \
                  (bf16*)Vs + (BUFN)*4096 + c_ * 8);                        \
    }                                                                       \
  } while (0)

  STAGE(0, 0);
  __syncthreads();

  for (int kt = 0; kt < ntiles; ++kt) {
    const int kv0 = kt * 64;
    const int buf = kt & 1;
    if (kt + 1 < ntiles) STAGE(buf ^ 1, kv0 + 64);
    if (kt <= qt) {
      const char* KtB = (const char*)Ks + buf * 8192;
      const char* VtB = (const char*)Vs + buf * 8192;
      const unsigned long long pb = mk[kt];
      const bool diag = (kt == qt);
      const bool domask = diag || (pb != 0ull);
#pragma unroll
      for (int half = 0; half < 2; ++half) {
        // ---- QK^T (swapped): S^T[kv 32][q 32], acc init -12 (fixed max)
        f32x16 s;
#pragma unroll
        for (int rg = 0; rg < 16; ++rg) s[rg] = -12.0f;
        __builtin_amdgcn_s_setprio(1);
#pragma unroll
        for (int hdk = 0; hdk < 4; ++hdk) {
          const bf16x8 kfr = *(const bf16x8*)(
              KtB + r31 * 256 + ((half * 128 + hdk * 32 + hi * 16) ^ swz));
          s = mfma32(kfr, qf[hdk], s);
        }
        __builtin_amdgcn_s_setprio(0);
        if (domask) {
#pragma unroll
          for (int rg = 0; rg < 16; ++rg) {
            const int kvt = half * 32 + (rg & 3) + 8 * (rg >> 2) + 4 * hi;
            const bool bad = (diag && (kv0 + kvt > row0 + r31)) ||
                             ((pb >> kvt) & 1ull);
            s[rg] = bad ? -1e30f : s[rg];
          }
        }
        // ---- p = exp2(s); rowsum (thread-local, q = r31)
        float pe[16];
#pragma unroll
        for (int rg = 0; rg < 16; ++rg) pe[rg] = exp2f(s[rg]);
        ls += (((pe[0] + pe[1]) + (pe[2] + pe[3])) +
               ((pe[4] + pe[5]) + (pe[6] + pe[7]))) +
              (((pe[8] + pe[9]) + (pe[10] + pe[11])) +
               ((pe[12] + pe[13]) + (pe[14] + pe[15])));
        // ---- build PV A-frags in registers + PV
#pragma unroll
        for (int j = 0; j < 2; ++j) {
          const unsigned a0 = pk2(pe[8 * j + 0], pe[8 * j + 1]);
          const unsigned a1 = pk2(pe[8 * j + 2], pe[8 * j + 3]);
          const unsigned b0 = pk2(pe[8 * j + 4], pe[8 * j + 5]);
          const unsigned b1 = pk2(pe[8 * j + 6], pe[8 * j + 7]);
          const unsigned xa0 = __shfl_xor(a0, 32, 64);
          const unsigned xa1 = __shfl_xor(a1, 32, 64);
          const unsigned xb0 = __shfl_xor(b0, 32, 64);
          const unsigned xb1 = __shfl_xor(b1, 32, 64);
          u32x4 wv;
          wv[0] = hi ? xb0 : a0;
          wv[1] = hi ? xb1 : a1;
          wv[2] = hi ? b0 : xa0;
          wv[3] = hi ? b1 : xa1;
          const bf16x8 paf = __builtin_bit_cast(bf16x8, wv);
          const int kvb = half * 64 + j * 32;  // byte base of kv columns
          const bf16x8 vf0 = *(const bf16x8*)(
              VtB + r31 * 256 + ((kvb + hi * 16) ^ swz));
          const bf16x8 vf1 = *(const bf16x8*)(
              VtB + r31 * 256 + ((128 + kvb + hi * 16) ^ swz));
          __builtin_amdgcn_s_setprio(1);
          o[0] = mfma32(paf, vf0, o[0]);
          o[1] = mfma32(paf, vf1, o[1]);
          __builtin_amdgcn_s_setprio(0);
        }
      }
    }
    __syncthreads();
  }

  // ---- epilogue: rowsum across hi halves; normalize; store
  ls += __shfl_xor(ls, 32, 64);
  const float inv = 1.0f / ls;  // valid for q = r31 on every lane
#pragma unroll
  for (int rg = 0; rg < 16; ++rg) {
    const int qrel = (rg & 3) + 8 * (rg >> 2) + 4 * hi;
    const float invq = __shfl(inv, qrel, 64);
    float* op = &out[((size_t)b * 2048 + row0 + qrel) * 1024 + h * 64 + r31];
    op[0] = o[0][rg] * invq;
    op[32] = o[1][rg] * invq;
  }
}

// ---------------------------------------------------------------------------
extern "C" void kernel_launch(void* const* d_in, const int* in_sizes, int n_in,
                              void* d_out, int out_size, void* d_ws,
                              size_t ws_size, hipStream_t stream) {
  const float* hs = (const float*)d_in[0];
  const int* amask = (const int*)d_in[1];
  const float* Wq = (const float*)d_in[2];
  const float* bq = (const float*)d_in[3];
  const float* Wk = (const float*)d_in[4];
  const float* bk = (const float*)d_in[5];
  const float* Wv = (const float*)d_in[6];
  const float* bv = (const float*)d_in[7];
  float* out = (float*)d_out;

  char* ws = (char*)d_ws;
  bf16* Xb = (bf16*)ws;                               // 8 MB: [4096][1024]
  bf16* Wb = (bf16*)(ws + 8ull * 1024 * 1024);        // 6 MB: [3072][1024]
  bf16* Qb = (bf16*)(ws + 14ull * 1024 * 1024);       // 8 MB: [32][2048][64]
  bf16* Kb = (bf16*)(ws + 22ull * 1024 * 1024);       // 8 MB: [32][2048][64]
  bf16* Vtb = (bf16*)(ws + 30ull * 1024 * 1024);      // 8 MB: [32][64][2048]

  cvt_all<<<7168, 256, 0, stream>>>(hs, Wq, Wk, Wv, Xb, Wb);
  gemm_qkv<<<768, 256, 0, stream>>>(Xb, Wb, bq, bk, bv, Qb, Kb, Vtb);
  flash_attn<<<512, 256, 0, stream>>>(Qb, Kb, Vtb, amask, out);
}

// Round 7
// 106.333 us; speedup vs baseline: 1.0097x; 1.0097x over previous
//
#include <hip/hip_runtime.h>

typedef __bf16 bf16;
typedef __bf16 bf16x4 __attribute__((ext_vector_type(4)));
typedef __bf16 bf16x8 __attribute__((ext_vector_type(8)));
typedef float f32x4 __attribute__((ext_vector_type(4)));
typedef float f32x16 __attribute__((ext_vector_type(16)));
typedef unsigned u32x4 __attribute__((ext_vector_type(4)));

#define DEV __device__ __forceinline__

typedef const __attribute__((address_space(1))) void gvoid_t;
typedef __attribute__((address_space(3))) void lvoid_t;

DEV void gload_lds16(const void* g, void* l) {
  __builtin_amdgcn_global_load_lds((gvoid_t*)g, (lvoid_t*)l, 16, 0, 0);
}

DEV f32x4 mfma16(bf16x8 a, bf16x8 b, f32x4 c) {
  return __builtin_amdgcn_mfma_f32_16x16x32_bf16(a, b, c, 0, 0, 0);
}
DEV f32x16 mfma32(bf16x8 a, bf16x8 b, f32x16 c) {
  return __builtin_amdgcn_mfma_f32_32x32x16_bf16(a, b, c, 0, 0, 0);
}

DEV unsigned pk2(float lo, float hi) {
  unsigned r;
  asm("v_cvt_pk_bf16_f32 %0, %1, %2" : "=v"(r) : "v"(lo), "v"(hi));
  return r;
}

// scores in exp2 domain: Q pre-scaled by 0.125 * log2(e) in the GEMM epilogue.
#define QSCALE 0.18033688011112042f

// ---------------------------------------------------------------------------
// Kernel A: fused f32 -> bf16 conversion of hidden_states + Wq|Wk|Wv.
// ---------------------------------------------------------------------------
__global__ __launch_bounds__(256) void cvt_all(
    const float* __restrict__ hs, const float* __restrict__ Wq,
    const float* __restrict__ Wk, const float* __restrict__ Wv,
    bf16* __restrict__ Xb, bf16* __restrict__ Wb) {
  const int i = blockIdx.x * 256 + threadIdx.x;  // float4 index
  const float* src;
  bf16* dst;
  int off;
  if (i < 1048576) {
    src = hs; dst = Xb; off = i;
  } else {
    const int j = i - 1048576;
    const int sel = j >> 18;
    off = j & 262143;
    src = (sel == 0) ? Wq : (sel == 1) ? Wk : Wv;
    dst = Wb + (size_t)sel * 1048576;
  }
  float4 f = reinterpret_cast<const float4*>(src)[off];
  bf16x4 o;
  o[0] = (bf16)f.x; o[1] = (bf16)f.y; o[2] = (bf16)f.z; o[3] = (bf16)f.w;
  reinterpret_cast<bf16x4*>(dst)[off] = o;
}

// ---------------------------------------------------------------------------
// Kernel B: fused QKV projection GEMM (unchanged).
// ---------------------------------------------------------------------------
__global__ __launch_bounds__(256) void gemm_qkv(
    const bf16* __restrict__ X, const bf16* __restrict__ W,
    const float* __restrict__ bq, const float* __restrict__ bk,
    const float* __restrict__ bv,
    bf16* __restrict__ Q, bf16* __restrict__ Kb, bf16* __restrict__ Vt) {
  __shared__ bf16 As[128 * 64];
  __shared__ bf16 Bs[128 * 64];
  const int t = threadIdx.x;
  const int lane = t & 63, w = t >> 6;
  const int wr = w >> 1, wc = w & 1;
  const int bid = blockIdx.x;
  const int swzb = (bid & 7) * 96 + (bid >> 3);  // XCD swizzle, 768%8==0
  const int m0 = (swzb / 24) * 128;
  const int n0 = (swzb % 24) * 128;
  const int cl = lane & 15, g8 = (lane >> 4) * 8;

  f32x4 acc[4][4];
  for (int mi = 0; mi < 4; ++mi)
    for (int ni = 0; ni < 4; ++ni)
      for (int r = 0; r < 4; ++r) acc[mi][ni][r] = 0.0f;

  for (int k0 = 0; k0 < 1024; k0 += 64) {
#pragma unroll
    for (int i = 0; i < 4; ++i) {
      int c = i * 256 + t;
      int row = c >> 3, col8 = (c & 7) * 8;
      gload_lds16(X + (size_t)(m0 + row) * 1024 + k0 + col8, As + c * 8);
      gload_lds16(W + (size_t)(n0 + row) * 1024 + k0 + col8, Bs + c * 8);
    }
    __syncthreads();
#pragma unroll
    for (int kk = 0; kk < 64; kk += 32) {
      bf16x8 a[4], b[4];
#pragma unroll
      for (int mi = 0; mi < 4; ++mi)
        a[mi] = *(const bf16x8*)&As[(wr * 64 + mi * 16 + cl) * 64 + kk + g8];
#pragma unroll
      for (int ni = 0; ni < 4; ++ni)
        b[ni] = *(const bf16x8*)&Bs[(wc * 64 + ni * 16 + cl) * 64 + kk + g8];
      __builtin_amdgcn_s_setprio(1);
#pragma unroll
      for (int mi = 0; mi < 4; ++mi)
#pragma unroll
        for (int ni = 0; ni < 4; ++ni)
          acc[mi][ni] = mfma16(a[mi], b[ni], acc[mi][ni]);
      __builtin_amdgcn_s_setprio(0);
    }
    __syncthreads();
  }

  const int rq = (lane >> 4) * 4;
#pragma unroll
  for (int mi = 0; mi < 4; ++mi) {
#pragma unroll
    for (int ni = 0; ni < 4; ++ni) {
      const int n = n0 + wc * 64 + ni * 16 + cl;
      const int mbase = m0 + wr * 64 + mi * 16 + rq;
      const int b = mbase >> 11, s0 = mbase & 2047;
      if (n < 1024) {
        const float bias = bq[n];
        const int h = n >> 6, hd = n & 63;
#pragma unroll
        for (int r = 0; r < 4; ++r)
          Q[(((size_t)(b * 16 + h)) * 2048 + s0 + r) * 64 + hd] =
              (bf16)((acc[mi][ni][r] + bias) * QSCALE);
      } else if (n < 2048) {
        const int n2 = n - 1024;
        const float bias = bk[n2];
        const int h = n2 >> 6, hd = n2 & 63;
#pragma unroll
        for (int r = 0; r < 4; ++r)
          Kb[(((size_t)(b * 16 + h)) * 2048 + s0 + r) * 64 + hd] =
              (bf16)(acc[mi][ni][r] + bias);
      } else {
        const int n2 = n - 2048;
        const float bias = bv[n2];
        const int h = n2 >> 6, hd = n2 & 63;
        bf16x4 pk;
#pragma unroll
        for (int r = 0; r < 4; ++r) pk[r] = (bf16)(acc[mi][ni][r] + bias);
        *(bf16x4*)&Vt[(((size_t)(b * 16 + h)) * 64 + hd) * 2048 + s0] = pk;
      }
    }
  }
}

// ---------------------------------------------------------------------------
// Kernel C: causal flash attention v7 — v6 structure + KV-parity wave split.
// Block = 8 waves (512 thr): 4 q-slots (g = w>>1) x 2 kv-parity splits
// (par = w&1). Each wave sweeps kv tiles kt ≡ par (mod 2), kt <= qt.
// KV tile pairs double-buffered in a 64 KB LDS arena ([32][128]-packed,
// 4-bit XOR swizzle). Fixed-max softmax (acc init -12, p = exp2(s)) makes
// the parity split associative: partials combine after the sweep through
// the dead KV arena (O = O0+O1, l = l0+l1). P never touches LDS.
// ---------------------------------------------------------------------------
__global__ __launch_bounds__(512, 4) void flash_attn(
    const bf16* __restrict__ Q, const bf16* __restrict__ K,
    const bf16* __restrict__ Vt, const int* __restrict__ amask,
    float* __restrict__ out) {
  __shared__ __align__(16) char arena[65536];
  __shared__ unsigned long long mk[32];
  bf16* Karena = (bf16*)arena;             // [4][4096] bf16 (pair,par)
  bf16* Varena = (bf16*)(arena + 32768);   // [4][4096] bf16
  const int t = threadIdx.x, lane = t & 63, w = t >> 6;
  const int bh = blockIdx.x & 31;  // same bh -> same XCD
  const int p = blockIdx.x >> 5;   // 0..15
  const int b = bh >> 4, h = bh & 15;
  const int g = w >> 1, par = w & 1;
  const int qt = (g < 2) ? (31 - p) : p;
  const int row0 = qt * 64 + (g & 1) * 32;
  const int r31 = lane & 31, hi = lane >> 5;
  const int swz = (r31 & 15) << 4;
  const int ntb = 32 - p;             // kv tiles this block stages
  const int nsuper = (ntb + 1) >> 1;  // tile pairs

  const bf16* Qp = Q + (size_t)bh * 2048 * 64;
  const bf16* Kp = K + (size_t)bh * 2048 * 64;
  const bf16* Vp = Vt + (size_t)bh * 64 * 2048;

  // Q^T B-fragments: lane holds col q=r31, k(hd) = hdk*16 + hi*8 .. +8
  bf16x8 qf[4];
#pragma unroll
  for (int hdk = 0; hdk < 4; ++hdk)
    qf[hdk] = *(const bf16x8*)&Qp[(size_t)(row0 + r31) * 64 + hdk * 16 + hi * 8];

  f32x16 o[2];
#pragma unroll
  for (int hb = 0; hb < 2; ++hb)
#pragma unroll
    for (int rg = 0; rg < 16; ++rg) o[hb][rg] = 0.0f;
  float ls = 0.0f;

  // prologue: pad-mask ballots for all 32 tiles (8 waves x 4)
#pragma unroll
  for (int i = 0; i < 4; ++i) {
    const int kt = w * 4 + i;
    const unsigned long long bal =
        __ballot(amask[b * 2048 + kt * 64 + lane] != 0);
    if (lane == 0) mk[kt] = bal;
  }
  // staging: one KV tile (K 8KB + V 8KB) per call, 512 threads x 16 B.
#define STAGE(BIDX, KVB)                                                     \
  do {                                                                       \
    const int r_ = t >> 4, u_ = (t & 15) ^ (r_ & 15);                        \
    const int rr_ = (u_ >> 3) * 32 + r_, gb_ = (u_ & 7) * 8;                 \
    gload_lds16(Kp + (size_t)((KVB) + rr_) * 64 + gb_,                       \
                Karena + (BIDX)*4096 + t * 8);                               \
    gload_lds16(Vp + (size_t)rr_ * 2048 + (KVB) + gb_,                       \
                Varena + (BIDX)*4096 + t * 8);                               \
  } while (0)

  STAGE(0, 0);    // tile 0 -> (pair0, par0)
  STAGE(1, 64);   // tile 1 -> (pair0, par1)  (ntb >= 17 always)
  __syncthreads();

  for (int s = 0; s < nsuper; ++s) {
    const int pairbuf = s & 1;
    const int tn = 2 * s + 2;  // prefetch pair s+1
    if (tn < ntb) STAGE((pairbuf ^ 1) * 2 + 0, tn * 64);
    if (tn + 1 < ntb) STAGE((pairbuf ^ 1) * 2 + 1, (tn + 1) * 64);
    const int kt = 2 * s + par;
    if (kt <= qt) {
      const int kv0 = kt * 64;
      const int bidx = pairbuf * 2 + par;
      const char* KtB = (const char*)(Karena + bidx * 4096);
      const char* VtB = (const char*)(Varena + bidx * 4096);
      const unsigned long long pb = mk[kt];
      const bool diag = (kt == qt);
      const bool domask = diag || (pb != 0ull);
#pragma unroll
      for (int half = 0; half < 2; ++half) {
        // ---- QK^T (swapped): S^T[kv 32][q 32], acc init -12 (fixed max)
        f32x16 s4;
#pragma unroll
        for (int rg = 0; rg < 16; ++rg) s4[rg] = -12.0f;
        __builtin_amdgcn_s_setprio(1);
#pragma unroll
        for (int hdk = 0; hdk < 4; ++hdk) {
          const bf16x8 kfr = *(const bf16x8*)(
              KtB + r31 * 256 + ((half * 128 + hdk * 32 + hi * 16) ^ swz));
          s4 = mfma32(kfr, qf[hdk], s4);
        }
        __builtin_amdgcn_s_setprio(0);
        if (domask) {
#pragma unroll
          for (int rg = 0; rg < 16; ++rg) {
            const int kvt = half * 32 + (rg & 3) + 8 * (rg >> 2) + 4 * hi;
            const bool bad = (diag && (kv0 + kvt > row0 + r31)) ||
                             ((pb >> kvt) & 1ull);
            s4[rg] = bad ? -1e30f : s4[rg];
          }
        }
        // ---- p = exp2(s); rowsum (thread-local, q = r31)
        float pe[16];
#pragma unroll
        for (int rg = 0; rg < 16; ++rg) pe[rg] = exp2f(s4[rg]);
        ls += (((pe[0] + pe[1]) + (pe[2] + pe[3])) +
               ((pe[4] + pe[5]) + (pe[6] + pe[7]))) +
              (((pe[8] + pe[9]) + (pe[10] + pe[11])) +
               ((pe[12] + pe[13]) + (pe[14] + pe[15])));
        // ---- build PV A-frags in registers + PV
#pragma unroll
        for (int j = 0; j < 2; ++j) {
          const unsigned a0 = pk2(pe[8 * j + 0], pe[8 * j + 1]);
          const unsigned a1 = pk2(pe[8 * j + 2], pe[8 * j + 3]);
          const unsigned b0 = pk2(pe[8 * j + 4], pe[8 * j + 5]);
          const unsigned b1 = pk2(pe[8 * j + 6], pe[8 * j + 7]);
          const unsigned xa0 = __shfl_xor(a0, 32, 64);
          const unsigned xa1 = __shfl_xor(a1, 32, 64);
          const unsigned xb0 = __shfl_xor(b0, 32, 64);
          const unsigned xb1 = __shfl_xor(b1, 32, 64);
          u32x4 wv;
          wv[0] = hi ? xb0 : a0;
          wv[1] = hi ? xb1 : a1;
          wv[2] = hi ? b0 : xa0;
          wv[3] = hi ? b1 : xa1;
          const bf16x8 paf = __builtin_bit_cast(bf16x8, wv);
          const int kvb = half * 64 + j * 32;  // byte base of kv columns
          const bf16x8 vf0 = *(const bf16x8*)(
              VtB + r31 * 256 + ((kvb + hi * 16) ^ swz));
          const bf16x8 vf1 = *(const bf16x8*)(
              VtB + r31 * 256 + ((128 + kvb + hi * 16) ^ swz));
          __builtin_amdgcn_s_setprio(1);
          o[0] = mfma32(paf, vf0, o[0]);
          o[1] = mfma32(paf, vf1, o[1]);
          __builtin_amdgcn_s_setprio(0);
        }
      }
    }
    __syncthreads();
  }

  // ---- combine parity partials through the dead KV arena
  ls += __shfl_xor(ls, 32, 64);  // full parity-partial rowsum for q = r31
  float* Op = (float*)arena;            // [4][32][64] f32
  float* Lp = (float*)(arena + 32768);  // [4][32] f32
  if (par == 1) {
    float* Og = Op + g * 2048;
#pragma unroll
    for (int rg = 0; rg < 16; ++rg) {
      const int qrel = (rg & 3) + 8 * (rg >> 2) + 4 * hi;
      Og[qrel * 64 + r31] = o[0][rg];
      Og[qrel * 64 + 32 + r31] = o[1][rg];
    }
    if (lane < 32) Lp[g * 32 + r31] = ls;
  }
  __syncthreads();
  if (par == 0) {
    const float lt = ls + Lp[g * 32 + r31];
    const float inv = 1.0f / lt;  // valid for q = r31 on every lane
    const float* Og = Op + g * 2048;
#pragma unroll
    for (int rg = 0; rg < 16; ++rg) {
      const int qrel = (rg & 3) + 8 * (rg >> 2) + 4 * hi;
      const float invq = __shfl(inv, qrel, 64);
      float* op = &out[((size_t)b * 2048 + row0 + qrel) * 1024 + h * 64 + r31];
      op[0] = (o[0][rg] + Og[qrel * 64 + r31]) * invq;
      op[32] = (o[1][rg] + Og[qrel * 64 + 32 + r31]) * invq;
    }
  }
}

// ---------------------------------------------------------------------------
extern "C" void kernel_launch(void* const* d_in, const int* in_sizes, int n_in,
                              void* d_out, int out_size, void* d_ws,
                              size_t ws_size, hipStream_t stream) {
  const float* hs = (const float*)d_in[0];
  const int* amask = (const int*)d_in[1];
  const float* Wq = (const float*)d_in[2];
  const float* bq = (const float*)d_in[3];
  const float* Wk = (const float*)d_in[4];
  const float* bk = (const float*)d_in[5];
  const float* Wv = (const float*)d_in[6];
  const float* bv = (const float*)d_in[7];
  float* out = (float*)d_out;

  char* ws = (char*)d_ws;
  bf16* Xb = (bf16*)ws;                               // 8 MB: [4096][1024]
  bf16* Wb = (bf16*)(ws + 8ull * 1024 * 1024);        // 6 MB: [3072][1024]
  bf16* Qb = (bf16*)(ws + 14ull * 1024 * 1024);       // 8 MB: [32][2048][64]
  bf16* Kb = (bf16*)(ws + 22ull * 1024 * 1024);       // 8 MB: [32][2048][64]
  bf16* Vtb = (bf16*)(ws + 30ull * 1024 * 1024);      // 8 MB: [32][64][2048]

  cvt_all<<<7168, 256, 0, stream>>>(hs, Wq, Wk, Wv, Xb, Wb);
  gemm_qkv<<<768, 256, 0, stream>>>(Xb, Wb, bq, bk, bv, Qb, Kb, Vtb);
  flash_attn<<<512, 512, 0, stream>>>(Qb, Kb, Vtb, amask, out);
}